// Round 8
// baseline (350.102 us; speedup 1.0000x reference)
//
#include <hip/hip_runtime.h>
#include <math.h>

typedef __attribute__((ext_vector_type(8))) short bf16x8;
typedef __attribute__((ext_vector_type(4))) float f32x4;

namespace {

constexpr int B_ = 8, C_ = 512, H_ = 96, W_ = 96;
constexpr int HP = 48, WP = 48, N_ = HP * WP;   // pooled spatial, N=2304
constexpr int KD = 256, VD = 256, OD = 512;
constexpr int NSPLIT = 4;                        // KV splits
constexpr float EPSV = 1e-5f;
// softmax scale folded into qkT: s = (q*SCH)·(k*SCH) is in exp2 domain
// SCH = sqrt(key_dim^-0.5 * log2(e))
constexpr float SCH = 0.30028060f;

// workspace byte offsets
constexpr size_t BOFF_XPT = 0;                                       // bf16 [B][N][C]
constexpr size_t BOFF_QKT = BOFF_XPT + (size_t)B_ * N_ * C_ * 2;     // bf16 [B][N][KD]
constexpr size_t BOFF_VAL = BOFF_QKT + (size_t)B_ * N_ * KD * 2;     // bf16 [B][VD][N]
constexpr size_t BOFF_CTX = BOFF_VAL + (size_t)B_ * VD * N_ * 2;     // bf16 [B][N][VD]
constexpr size_t BOFF_W2  = BOFF_CTX + (size_t)B_ * N_ * VD * 2;     // bf16 [512][512]
constexpr size_t BOFF_WF  = BOFF_W2  + (size_t)512 * 512 * 2;        // bf16 [OD][VD]
constexpr size_t BOFF_BF  = BOFF_WF  + (size_t)OD * VD * 2;          // fp32 [OD]
constexpr size_t BOFF_PRT = BOFF_BF  + (size_t)OD * 4;               // bf16 [S][B][N][VD]
constexpr size_t BOFF_PM  = BOFF_PRT + (size_t)NSPLIT * B_ * N_ * VD * 2;  // f32 [S][B][N]
constexpr size_t BOFF_PL  = BOFF_PM  + (size_t)NSPLIT * B_ * N_ * 4;       // f32 [S][B][N]
// Z bf16 [B][OD][N] (18.9MB) overlays xpT (18.9MB), dead by then

} // namespace

__device__ __forceinline__ ushort f2bf(float f) {
    union { float f; unsigned u; } x; x.f = f;
    unsigned r = x.u + 0x7FFFu + ((x.u >> 16) & 1u);
    return (ushort)(r >> 16);
}

__device__ __forceinline__ float bf2f(ushort u) {
    union { unsigned u; float f; } x; x.u = ((unsigned)u) << 16;
    return x.f;
}

__device__ __forceinline__ void gload_lds16(const void* g, void* l) {
    __builtin_amdgcn_global_load_lds(
        (const __attribute__((address_space(1))) unsigned int*)g,
        (__attribute__((address_space(3))) unsigned int*)l, 16, 0, 0);
}

// ------------------------ fused maxpool 2x2 + transpose + bf16: x -> xpT[b][n][c]
__global__ __launch_bounds__(192) void pool_t_kernel(const float* __restrict__ x,
                                                     ushort* __restrict__ xpT) {
    __shared__ float ps[64][49];
    const int gid = blockIdx.x;
    const int ct = gid & 7;          // c-tile (64 channels)
    const int tmp = gid >> 3;
    const int oh = tmp % 48;
    const int b  = tmp / 48;
    const int t = threadIdx.x;
    const int ow = t % 48, ci = t / 48;   // ci 0..3

    const int c0 = ct * 64;
#pragma unroll
    for (int pass = 0; pass < 16; ++pass) {
        const int c = pass * 4 + ci;
        const float* px = x + (((size_t)b * C_ + c0 + c) * H_ + 2 * oh) * W_ + 2 * ow;
        float2 a = *reinterpret_cast<const float2*>(px);
        float2 d = *reinterpret_cast<const float2*>(px + W_);
        ps[c][ow] = fmaxf(fmaxf(a.x, a.y), fmaxf(d.x, d.y));
    }
    __syncthreads();
    const int cc2 = (t & 31) * 2;
    const int nr0 = t >> 5;          // 0..5
#pragma unroll
    for (int pass = 0; pass < 8; ++pass) {
        const int nr = pass * 6 + nr0;     // 0..47
        ushort2 p2;
        p2.x = f2bf(ps[cc2][nr]);
        p2.y = f2bf(ps[cc2 + 1][nr]);
        *reinterpret_cast<ushort2*>(&xpT[((size_t)b * N_ + oh * 48 + nr) * C_ + c0 + cc2]) = p2;
    }
}

// ---------------- prep: pack W2 bf16 | fuse Wfb = bf16(Wr@Ww) | bfuse = Wr@bw
__global__ __launch_bounds__(256) void prep_kernel(const float* __restrict__ Wk,
                                                   const float* __restrict__ Wv,
                                                   const float* __restrict__ Wr,
                                                   const float* __restrict__ Ww,
                                                   const float* __restrict__ bw,
                                                   ushort* __restrict__ W2,
                                                   ushort* __restrict__ Wfb,
                                                   float* __restrict__ bfb) {
    const int blk = blockIdx.x;
    if (blk < 512) {
        const int m = blk;
        const float* src = (m < 256) ? (Wk + (size_t)m * 512) : (Wv + (size_t)(m - 256) * 512);
        const int k = threadIdx.x * 2;
        float2 v = *reinterpret_cast<const float2*>(src + k);
        ushort2 p; p.x = f2bf(v.x); p.y = f2bf(v.y);
        *reinterpret_cast<ushort2*>(&W2[(size_t)m * 512 + k]) = p;
    } else if (blk < 1024) {
        const int o = blk - 512;
        const int v = threadIdx.x;
        float s = 0.f;
        for (int c = 0; c < OD; ++c)
            s = fmaf(Wr[(size_t)o * OD + c], Ww[(size_t)c * VD + v], s);
        Wfb[(size_t)o * VD + v] = f2bf(s);
    } else {
        const int o = (blk - 1024) * 256 + threadIdx.x;
        float s = 0.f;
        for (int c = 0; c < OD; ++c) s = fmaf(Wr[(size_t)o * OD + c], bw[c], s);
        bfb[o] = s;
    }
}

// ------------------------------------- qkv MFMA GEMM (LDS-staged, 2-phase):
// [Wk|Wv](512x512) @ xpT^T -> qkT bf16 [b][n][kd] (BN+ReLU, x SCH) / val bf16 [b][v][n]
__global__ __launch_bounds__(256) void qkv_mfma(
    const ushort* __restrict__ W2, const ushort* __restrict__ xpT,
    const float* __restrict__ kg, const float* __restrict__ kb,
    const float* __restrict__ km, const float* __restrict__ kv,
    const float* __restrict__ bv,
    ushort* __restrict__ qkT, ushort* __restrict__ val) {
    __shared__ ushort Al[2][4096];   // 8KB tile: [kc 2][64 m][32 k], 64B-row swizzled
    __shared__ ushort Bl[2][4096];

    const int id = blockIdx.x;
    const int b = id & 7;
    const int t = id >> 3;           // 0..287
    const int my = t & 7;            // m-tile
    const int nx = t >> 3;           // 0..35
    const int w = threadIdx.x >> 6, l = threadIdx.x & 63;
    const int lr = l & 15, lg = l >> 4;
    const int rbq = (lg * 8) ^ (((lr >> 1) & 3) << 3);

    const ushort* srcA = W2 + (size_t)(my * 64) * 512;              // ld 512
    const ushort* srcB = xpT + ((size_t)b * N_ + nx * 64) * 512;    // ld 512

    auto stage64 = [&](const ushort* src, int koff, char* lbase) {
#pragma unroll
        for (int j = 0; j < 2; ++j) {
            const int prow = j * 64 + w * 16 + (l >> 2);   // 0..127
            const int row = prow & 63;
            const int kc = prow >> 6;
            const int cb = ((l & 3) * 16) ^ (((row >> 1) & 3) << 4);
            const char* s = (const char*)(src + (size_t)row * 512 + koff) + kc * 64 + cb;
            gload_lds16(s, lbase + j * 4096 + w * 1024);
        }
    };

    stage64(srcA, 0, (char*)&Al[0][0]);
    stage64(srcB, 0, (char*)&Bl[0][0]);
    stage64(srcA, 64, (char*)&Al[1][0]);
    stage64(srcB, 64, (char*)&Bl[1][0]);

    f32x4 acc[4];
#pragma unroll
    for (int nt = 0; nt < 4; ++nt) acc[nt] = (f32x4){0.f, 0.f, 0.f, 0.f};

    for (int ks = 0; ks < 8; ++ks) {
        if (ks < 7) { asm volatile("s_waitcnt vmcnt(4)" ::: "memory"); }
        else        { asm volatile("s_waitcnt vmcnt(0)" ::: "memory"); }
        __builtin_amdgcn_s_barrier();
        __builtin_amdgcn_sched_barrier(0);
        const ushort* Ab = &Al[ks & 1][0];
        const ushort* Bb = &Bl[ks & 1][0];
        __builtin_amdgcn_s_setprio(1);
#pragma unroll
        for (int kc = 0; kc < 2; ++kc) {
            bf16x8 af = *reinterpret_cast<const bf16x8*>(Ab + kc * 2048 + (w * 16 + lr) * 32 + rbq);
#pragma unroll
            for (int nt = 0; nt < 4; ++nt) {
                bf16x8 bfr = *reinterpret_cast<const bf16x8*>(Bb + kc * 2048 + (nt * 16 + lr) * 32 + rbq);
                acc[nt] = __builtin_amdgcn_mfma_f32_16x16x32_bf16(af, bfr, acc[nt], 0, 0, 0);
            }
        }
        __builtin_amdgcn_s_setprio(0);
        __builtin_amdgcn_sched_barrier(0);
        __builtin_amdgcn_s_barrier();
        if (ks < 6) {
            stage64(srcA, (ks + 2) * 64, (char*)&Al[ks & 1][0]);
            stage64(srcB, (ks + 2) * 64, (char*)&Bl[ks & 1][0]);
        }
    }

    const int m0 = my * 64 + w * 16;
    if (m0 < 256) {
        float inv[4], add[4];
#pragma unroll
        for (int j = 0; j < 4; ++j) {
            int o = m0 + lg * 4 + j;
            inv[j] = kg[o] * rsqrtf(kv[o] + EPSV);
            add[j] = kb[o] - km[o] * inv[j];
        }
#pragma unroll
        for (int nt = 0; nt < 4; ++nt) {
            int n = nx * 64 + nt * 16 + lr;
            ushort4 q4;
            q4.x = f2bf(fmaxf(acc[nt][0] * inv[0] + add[0], 0.f) * SCH);
            q4.y = f2bf(fmaxf(acc[nt][1] * inv[1] + add[1], 0.f) * SCH);
            q4.z = f2bf(fmaxf(acc[nt][2] * inv[2] + add[2], 0.f) * SCH);
            q4.w = f2bf(fmaxf(acc[nt][3] * inv[3] + add[3], 0.f) * SCH);
            *reinterpret_cast<ushort4*>(&qkT[((size_t)b * N_ + n) * KD + m0 + lg * 4]) = q4;
        }
    } else {
#pragma unroll
        for (int j = 0; j < 4; ++j) {
            int vch = m0 - 256 + lg * 4 + j;
            float bb = bv[vch];
#pragma unroll
            for (int nt = 0; nt < 4; ++nt) {
                int n = nx * 64 + nt * 16 + lr;
                val[((size_t)b * VD + vch) * N_ + n] = f2bf(acc[nt][j] + bb);
            }
        }
    }
}

// ------------------------------------------------------ LDS-staged MFMA flash attention
// 8 waves / 512 thr; 128 q-rows per block; 4-way KV split (18 tiles of 32 keys).
// K+V double-buffered (72KB LDS -> 2 blocks/CU = 16 waves/CU). Staging tiles
// shared by 8 waves (2x efficiency vs 4-wave). Defer-max check is lane-local
// (no cross-lane reduce on hot path); scale pre-folded into qkT (exp2 domain).
__global__ __launch_bounds__(512, 4) void attn_mfma(const ushort* __restrict__ qkT,
                                                    const ushort* __restrict__ val,
                                                    ushort* __restrict__ part,
                                                    float* __restrict__ pm,
                                                    float* __restrict__ pl) {
    __shared__ ushort Kl[2][8192];   // 2 x 16KB: [kc 8][m 32][32 kd]
    __shared__ ushort Vl[2][8192];   // 2 x 16KB: [v 256][m 32]
    __shared__ ushort Pl[8][512];    // per-wave P [16 q][32 m]

    const int id = blockIdx.x;
    const int b  = id & 7;           // XCD-pinned batch
    const int rest = id >> 3;        // 0..71
    const int s  = rest & 3;         // KV quarter
    const int qt = rest >> 2;        // 0..17
    const int q0 = qt * 128;
    const int t0 = s * 18;           // first key-tile of this split
    const int w  = threadIdx.x >> 6; // 0..7
    const int l  = threadIdx.x & 63;
    const int lr = l & 15, lg = l >> 4;

    const ushort* Qb = qkT + (size_t)b * N_ * KD;
    const ushort* Vb = val + (size_t)b * VD * N_;

    const int rb = lr * 32 + ((lg * 8) ^ (((lr >> 1) & 3) << 3));

    // resident Q fragments (16 q-rows per wave)
    bf16x8 qf[8];
    {
        const ushort* qrow = Qb + (size_t)(q0 + w * 16 + lr) * KD + lg * 8;
#pragma unroll
        for (int kc = 0; kc < 8; ++kc)
            qf[kc] = *reinterpret_cast<const bf16x8*>(qrow + kc * 32);
    }
    asm volatile("s_waitcnt vmcnt(0)" ::: "memory");

    // each wave stages 2KB of each 16KB tile (2 issues)
    auto stage_K = [&](int itx, int buf) {
#pragma unroll
        for (int j = 0; j < 2; ++j) {
            const int prow = j * 128 + w * 16 + (l >> 2);  // kc*32 + m, 0..255
            const int m = prow & 31;
            const int kc = prow >> 5;
            const int cb = ((l & 3) * 16) ^ (((m >> 1) & 3) << 4);
            const char* src = (const char*)Qb + (size_t)(itx * 32 + m) * (KD * 2) + kc * 64 + cb;
            gload_lds16(src, (char*)(&Kl[buf][0]) + j * 8192 + w * 1024);
        }
    };
    auto stage_V = [&](int itx, int buf) {
#pragma unroll
        for (int j = 0; j < 2; ++j) {
            const int r = j * 128 + w * 16 + (l >> 2);     // v-row 0..255
            const int cb = ((l & 3) * 16) ^ (((r >> 1) & 3) << 4);
            const char* src = (const char*)Vb + (size_t)r * (N_ * 2) + itx * 64 + cb;
            gload_lds16(src, (char*)(&Vl[buf][0]) + j * 8192 + w * 1024);
        }
    };

    stage_K(t0, 0);      // queue/wave (oldest first): K0(2), V0(2), K1(2) = 6
    stage_V(t0, 0);
    stage_K(t0 + 1, 1);

    f32x4 O[16];
#pragma unroll
    for (int vt = 0; vt < 16; ++vt) O[vt] = (f32x4){0.f, 0.f, 0.f, 0.f};
    f32x4 Ol = (f32x4){0.f, 0.f, 0.f, 0.f};     // P row-sum accumulator (l)
    float mrun[4] = {-1e30f, -1e30f, -1e30f, -1e30f};   // log2 domain
    bf16x8 ones;
#pragma unroll
    for (int i = 0; i < 8; ++i) ones[i] = (short)0x3F80;   // bf16 1.0

    ushort* Pw = &Pl[w][0];

    for (int it = 0; it < 18; ++it) {
        const int cur = it & 1;
        // ---- K(it) ready: steady outstanding {K(it),V(it),K(it+1)}=6 -> 4
        if (it < 17) { asm volatile("s_waitcnt vmcnt(4)" ::: "memory"); }
        else         { asm volatile("s_waitcnt vmcnt(2)" ::: "memory"); }
        __builtin_amdgcn_s_barrier();
        __builtin_amdgcn_sched_barrier(0);
        if (it < 17) stage_V(t0 + it + 1, cur ^ 1);   // buf last read in PV(it-1)

        const ushort* Kc = &Kl[cur][0];

        // ---- S[16q x 32m] = Q K^T  (already exp2-domain: scale in qkT)
        f32x4 S0 = (f32x4){0.f, 0.f, 0.f, 0.f};
        f32x4 S1 = (f32x4){0.f, 0.f, 0.f, 0.f};
        __builtin_amdgcn_s_setprio(1);
#pragma unroll
        for (int kc = 0; kc < 8; ++kc) {
            bf16x8 k0 = *reinterpret_cast<const bf16x8*>(Kc + kc * 1024 + rb);
            bf16x8 k1 = *reinterpret_cast<const bf16x8*>(Kc + kc * 1024 + 512 + rb);
            S0 = __builtin_amdgcn_mfma_f32_16x16x32_bf16(qf[kc], k0, S0, 0, 0, 0);
            S1 = __builtin_amdgcn_mfma_f32_16x16x32_bf16(qf[kc], k1, S1, 0, 0, 0);
        }
        __builtin_amdgcn_s_setprio(0);

        // ---- defer-max: lane-local check only (no cross-lane reduce hot path)
        float lmax[4];
        bool ok = true;
#pragma unroll
        for (int r = 0; r < 4; ++r) {
            lmax[r] = fmaxf(S0[r], S1[r]);
            ok = ok && (lmax[r] <= mrun[r] + 11.5f);   // 11.5 bits ~ e^8
        }
        if (!__all(ok)) {
            float corr[4];
#pragma unroll
            for (int r = 0; r < 4; ++r) {
                float m2 = lmax[r];
#pragma unroll
                for (int off = 1; off < 16; off <<= 1) m2 = fmaxf(m2, __shfl_xor(m2, off, 16));
                const float mn = fmaxf(mrun[r], m2);
                corr[r] = exp2f(mrun[r] - mn);
                mrun[r] = mn;
            }
#pragma unroll
            for (int vt = 0; vt < 16; ++vt) {
                f32x4 o = O[vt];
                o[0] *= corr[0]; o[1] *= corr[1]; o[2] *= corr[2]; o[3] *= corr[3];
                O[vt] = o;
            }
            Ol[0] *= corr[0]; Ol[1] *= corr[1]; Ol[2] *= corr[2]; Ol[3] *= corr[3];
        }
#pragma unroll
        for (int r = 0; r < 4; ++r) {
            const int row = lg * 4 + r;
            const int sw = ((row >> 1) & 3) << 3;
            Pw[row * 32 + (lr ^ sw)] = f2bf(exp2f(S0[r] - mrun[r]));
            Pw[row * 32 + ((16 + lr) ^ sw)] = f2bf(exp2f(S1[r] - mrun[r]));
        }

        // ---- V(it) ready: outstanding {V(it),K(it+1),V(it+1)}=6 -> 4
        if (it < 17) { asm volatile("s_waitcnt vmcnt(4)" ::: "memory"); }
        else         { asm volatile("s_waitcnt vmcnt(0)" ::: "memory"); }
        __builtin_amdgcn_s_barrier();
        __builtin_amdgcn_sched_barrier(0);
        if (it < 16) stage_K(t0 + it + 2, cur);       // Kl[cur] free after QK(it)

        // ---- O += P V^T ; l += P ones^T
        bf16x8 pf = *reinterpret_cast<const bf16x8*>(Pw + rb);
        const ushort* Vc = &Vl[cur][0];
        __builtin_amdgcn_s_setprio(1);
        Ol = __builtin_amdgcn_mfma_f32_16x16x32_bf16(pf, ones, Ol, 0, 0, 0);
#pragma unroll
        for (int vt = 0; vt < 16; ++vt) {
            bf16x8 vf = *reinterpret_cast<const bf16x8*>(Vc + vt * 512 + rb);
            O[vt] = __builtin_amdgcn_mfma_f32_16x16x32_bf16(pf, vf, O[vt], 0, 0, 0);
        }
        __builtin_amdgcn_s_setprio(0);
    }

    // ---- epilogue: self-normalized partial (bf16) + per-row (m, l)
    float il[4];
#pragma unroll
    for (int r = 0; r < 4; ++r) il[r] = 1.0f / Ol[r];
    ushort* Pp = part + (((size_t)s * B_ + b) * N_ + q0 + w * 16) * VD;
#pragma unroll
    for (int vt = 0; vt < 16; ++vt) {
#pragma unroll
        for (int j = 0; j < 4; ++j)
            Pp[(size_t)(lg * 4 + j) * VD + vt * 16 + lr] = f2bf(O[vt][j] * il[j]);
    }
    if (lr == 0) {
#pragma unroll
        for (int r = 0; r < 4; ++r) {
            const size_t idx = ((size_t)s * B_ + b) * N_ + q0 + w * 16 + lg * 4 + r;
            pm[idx] = mrun[r];
            pl[idx] = Ol[r];
        }
    }
}

// ---------------------- merge 4 KV-split partials -> ctxT bf16 [b][n][v]
__global__ __launch_bounds__(256) void merge_kernel(const ushort* __restrict__ part,
                                                    const float* __restrict__ pm,
                                                    const float* __restrict__ pl,
                                                    ushort* __restrict__ ctxT) {
    const int row = blockIdx.x * 8 + (threadIdx.x >> 5);   // b*N + n
    const int lane = threadIdx.x & 31;
    const size_t RN = (size_t)B_ * N_;

    float m[NSPLIT], lv[NSPLIT];
#pragma unroll
    for (int si = 0; si < NSPLIT; ++si) {
        m[si]  = pm[si * RN + row];
        lv[si] = pl[si * RN + row];
    }
    float M = fmaxf(fmaxf(m[0], m[1]), fmaxf(m[2], m[3]));
    float wgt[NSPLIT], wsum = 0.f;
#pragma unroll
    for (int si = 0; si < NSPLIT; ++si) {
        wgt[si] = exp2f(m[si] - M) * lv[si];   // log2-domain maxes
        wsum += wgt[si];
    }
    const float inv = 1.0f / wsum;

    float acc[8] = {};
#pragma unroll
    for (int si = 0; si < NSPLIT; ++si) {
        bf16x8 p = *reinterpret_cast<const bf16x8*>(&part[(si * RN + row) * VD + lane * 8]);
        const float ws = wgt[si];
#pragma unroll
        for (int j = 0; j < 8; ++j) acc[j] = fmaf(ws, bf2f((ushort)p[j]), acc[j]);
    }
    ushort4 o0, o1;
    o0.x = f2bf(acc[0] * inv); o0.y = f2bf(acc[1] * inv);
    o0.z = f2bf(acc[2] * inv); o0.w = f2bf(acc[3] * inv);
    o1.x = f2bf(acc[4] * inv); o1.y = f2bf(acc[5] * inv);
    o1.z = f2bf(acc[6] * inv); o1.w = f2bf(acc[7] * inv);
    ushort* dst = ctxT + (size_t)row * VD + lane * 8;
    *reinterpret_cast<ushort4*>(dst) = o0;
    *reinterpret_cast<ushort4*>(dst + 4) = o1;
}

// ------------- out conv MFMA (LDS-staged) + folded BN: Z = bf16(bn(Wfb@ctxT^T + bfuse))
__global__ __launch_bounds__(256) void out_mfma(const ushort* __restrict__ Wfb,
                                                const float* __restrict__ bfuse,
                                                const float* __restrict__ rg,
                                                const float* __restrict__ rbta,
                                                const float* __restrict__ rm,
                                                const float* __restrict__ rv,
                                                const ushort* __restrict__ ctxT,
                                                ushort* __restrict__ Z) {
    __shared__ ushort Al[2][4096];
    __shared__ ushort Bl[2][4096];

    const int id = blockIdx.x;
    const int b = id & 7;
    const int t = id >> 3;           // 0..287
    const int my = t & 7;            // OD tile
    const int nx = t >> 3;           // 0..35
    const int w = threadIdx.x >> 6, l = threadIdx.x & 63;
    const int lr = l & 15, lg = l >> 4;
    const int rbq = (lg * 8) ^ (((lr >> 1) & 3) << 3);

    const ushort* srcA = Wfb + (size_t)(my * 64) * VD;               // ld 256
    const ushort* srcB = ctxT + ((size_t)b * N_ + nx * 64) * VD;     // ld 256

    auto stage64 = [&](const ushort* src, int koff, char* lbase) {
#pragma unroll
        for (int j = 0; j < 2; ++j) {
            const int prow = j * 64 + w * 16 + (l >> 2);
            const int row = prow & 63;
            const int kc = prow >> 6;
            const int cb = ((l & 3) * 16) ^ (((row >> 1) & 3) << 4);
            const char* s = (const char*)(src + (size_t)row * VD + koff) + kc * 64 + cb;
            gload_lds16(s, lbase + j * 4096 + w * 1024);
        }
    };

    stage64(srcA, 0, (char*)&Al[0][0]);
    stage64(srcB, 0, (char*)&Bl[0][0]);
    stage64(srcA, 64, (char*)&Al[1][0]);
    stage64(srcB, 64, (char*)&Bl[1][0]);

    f32x4 acc[4];
#pragma unroll
    for (int nt = 0; nt < 4; ++nt) acc[nt] = (f32x4){0.f, 0.f, 0.f, 0.f};

    for (int ks = 0; ks < 4; ++ks) {
        if (ks < 3) { asm volatile("s_waitcnt vmcnt(4)" ::: "memory"); }
        else        { asm volatile("s_waitcnt vmcnt(0)" ::: "memory"); }
        __builtin_amdgcn_s_barrier();
        __builtin_amdgcn_sched_barrier(0);
        const ushort* Ab = &Al[ks & 1][0];
        const ushort* Bb = &Bl[ks & 1][0];
        __builtin_amdgcn_s_setprio(1);
#pragma unroll
        for (int kc = 0; kc < 2; ++kc) {
            bf16x8 af = *reinterpret_cast<const bf16x8*>(Ab + kc * 2048 + (w * 16 + lr) * 32 + rbq);
#pragma unroll
            for (int nt = 0; nt < 4; ++nt) {
                bf16x8 bfr = *reinterpret_cast<const bf16x8*>(Bb + kc * 2048 + (nt * 16 + lr) * 32 + rbq);
                acc[nt] = __builtin_amdgcn_mfma_f32_16x16x32_bf16(af, bfr, acc[nt], 0, 0, 0);
            }
        }
        __builtin_amdgcn_s_setprio(0);
        __builtin_amdgcn_sched_barrier(0);
        __builtin_amdgcn_s_barrier();
        if (ks < 2) {
            stage64(srcA, (ks + 2) * 64, (char*)&Al[ks & 1][0]);
            stage64(srcB, (ks + 2) * 64, (char*)&Bl[ks & 1][0]);
        }
    }

    const int m0 = my * 64 + w * 16;
#pragma unroll
    for (int j = 0; j < 4; ++j) {
        const int o = m0 + lg * 4 + j;
        const float inv = rg[o] * rsqrtf(rv[o] + EPSV);
        const float add = rbta[o] - rm[o] * inv;
        const float bb = bfuse[o];
#pragma unroll
        for (int nt = 0; nt < 4; ++nt) {
            const int n = nx * 64 + nt * 16 + lr;
            Z[((size_t)b * OD + o) * N_ + n] = f2bf((acc[nt][j] + bb) * inv + add);
        }
    }
}

// --------------------------- bilinear upsample (align_corners) + ReLU, x4 vectorized
__global__ void upsample_kernel(const ushort* __restrict__ Z,
                                float* __restrict__ out) {
    const int total = B_ * OD * H_ * (W_ / 4);
    const float s = 47.0f / 95.0f;
    for (int idx = blockIdx.x * blockDim.x + threadIdx.x; idx < total;
         idx += gridDim.x * blockDim.x) {
        const int xq = idx % 24;
        const int t = idx / 24;
        const int y = t % H_;
        const int bo = t / H_;
        const float fy = y * s;
        const int y0 = (int)fy;
        const int y1 = min(y0 + 1, HP - 1);
        const float wy = fy - y0;
        const ushort* Zp = Z + (size_t)bo * N_;
        const ushort* r0 = Zp + y0 * WP;
        const ushort* r1 = Zp + y1 * WP;
        float4 o4;
        float* po = &o4.x;
#pragma unroll
        for (int j = 0; j < 4; ++j) {
            const int x = xq * 4 + j;
            const float fx = x * s;
            const int x0 = (int)fx;
            const int x1 = min(x0 + 1, WP - 1);
            const float wx = fx - x0;
            float v00 = bf2f(r0[x0]), v01 = bf2f(r0[x1]);
            float v10 = bf2f(r1[x0]), v11 = bf2f(r1[x1]);
            float a = v00 + (v01 - v00) * wx;
            float c = v10 + (v11 - v10) * wx;
            po[j] = fmaxf(a + (c - a) * wy, 0.f);
        }
        *reinterpret_cast<float4*>(out + (size_t)idx * 4) = o4;
    }
}

extern "C" void kernel_launch(void* const* d_in, const int* in_sizes, int n_in,
                              void* d_out, int out_size, void* d_ws, size_t ws_size,
                              hipStream_t stream) {
    const float* x  = (const float*)d_in[0];
    const float* Wk = (const float*)d_in[1];
    const float* kg = (const float*)d_in[2];
    const float* kb = (const float*)d_in[3];
    const float* km = (const float*)d_in[4];
    const float* kvv= (const float*)d_in[5];
    const float* Wv = (const float*)d_in[6];
    const float* bv = (const float*)d_in[7];
    const float* Ww = (const float*)d_in[8];
    const float* bw = (const float*)d_in[9];
    const float* Wr = (const float*)d_in[10];
    const float* rg = (const float*)d_in[11];
    const float* rb = (const float*)d_in[12];
    const float* rm = (const float*)d_in[13];
    const float* rv = (const float*)d_in[14];

    char* wsb = (char*)d_ws;
    ushort* xpT  = (ushort*)(wsb + BOFF_XPT);
    ushort* qkT  = (ushort*)(wsb + BOFF_QKT);
    ushort* valp = (ushort*)(wsb + BOFF_VAL);
    ushort* ctxT = (ushort*)(wsb + BOFF_CTX);
    ushort* W2   = (ushort*)(wsb + BOFF_W2);
    ushort* Wfb  = (ushort*)(wsb + BOFF_WF);
    float*  bfb  = (float*)(wsb + BOFF_BF);
    ushort* part = (ushort*)(wsb + BOFF_PRT);
    float*  pm   = (float*)(wsb + BOFF_PM);
    float*  pl   = (float*)(wsb + BOFF_PL);
    ushort* Z    = (ushort*)(wsb + BOFF_XPT);  // overlays xpT (dead after qkv)
    float*  out  = (float*)d_out;

    pool_t_kernel<<<8 * 48 * 8, 192, 0, stream>>>(x, xpT);
    prep_kernel<<<1026, 256, 0, stream>>>(Wk, Wv, Wr, Ww, bw, W2, Wfb, bfb);
    qkv_mfma<<<2304, 256, 0, stream>>>(W2, xpT, kg, kb, km, kvv, bv, qkT, valp);
    attn_mfma<<<576, 512, 0, stream>>>(qkT, valp, part, pm, pl);
    merge_kernel<<<(B_ * N_) / 8, 256, 0, stream>>>(part, pm, pl, ctxT);
    out_mfma<<<2304, 256, 0, stream>>>(Wfb, bfb, rg, rb, rm, rv, ctxT, Z);
    upsample_kernel<<<4096, 256, 0, stream>>>(Z, out);
}

// Round 9
// 335.219 us; speedup vs baseline: 1.0444x; 1.0444x over previous
//
#include <hip/hip_runtime.h>
#include <math.h>

typedef __attribute__((ext_vector_type(8))) short bf16x8;
typedef __attribute__((ext_vector_type(4))) float f32x4;

namespace {

constexpr int B_ = 8, C_ = 512, H_ = 96, W_ = 96;
constexpr int HP = 48, WP = 48, N_ = HP * WP;   // pooled spatial, N=2304
constexpr int KD = 256, VD = 256, OD = 512;
constexpr int NSPLIT = 4;                        // KV splits
constexpr float EPSV = 1e-5f;
// softmax scale folded into qkT: s = (q*SCH)·(k*SCH) is in exp2 domain
// SCH = sqrt(key_dim^-0.5 * log2(e))
constexpr float SCH = 0.30028060f;

// workspace byte offsets
constexpr size_t BOFF_XPT = 0;                                       // bf16 [B][N][C]
constexpr size_t BOFF_QKT = BOFF_XPT + (size_t)B_ * N_ * C_ * 2;     // bf16 [B][N][KD]
constexpr size_t BOFF_VAL = BOFF_QKT + (size_t)B_ * N_ * KD * 2;     // bf16 [B][VD][N]
constexpr size_t BOFF_CTX = BOFF_VAL + (size_t)B_ * VD * N_ * 2;     // bf16 [B][N][VD]
constexpr size_t BOFF_W2  = BOFF_CTX + (size_t)B_ * N_ * VD * 2;     // bf16 [512][512]
constexpr size_t BOFF_WF  = BOFF_W2  + (size_t)512 * 512 * 2;        // bf16 [OD][VD]
constexpr size_t BOFF_BF  = BOFF_WF  + (size_t)OD * VD * 2;          // fp32 [OD]
constexpr size_t BOFF_PRT = BOFF_BF  + (size_t)OD * 4;               // bf16 [S][B][N][VD]
constexpr size_t BOFF_PM  = BOFF_PRT + (size_t)NSPLIT * B_ * N_ * VD * 2;  // f32 [S][B][N]
constexpr size_t BOFF_PL  = BOFF_PM  + (size_t)NSPLIT * B_ * N_ * 4;       // f32 [S][B][N]
// Z bf16 [B][OD][N] (18.9MB) overlays xpT (18.9MB), dead by then

} // namespace

__device__ __forceinline__ ushort f2bf(float f) {
    union { float f; unsigned u; } x; x.f = f;
    unsigned r = x.u + 0x7FFFu + ((x.u >> 16) & 1u);
    return (ushort)(r >> 16);
}

__device__ __forceinline__ float bf2f(ushort u) {
    union { unsigned u; float f; } x; x.u = ((unsigned)u) << 16;
    return x.f;
}

__device__ __forceinline__ void gload_lds16(const void* g, void* l) {
    __builtin_amdgcn_global_load_lds(
        (const __attribute__((address_space(1))) unsigned int*)g,
        (__attribute__((address_space(3))) unsigned int*)l, 16, 0, 0);
}

// ------------------------ fused maxpool 2x2 + transpose + bf16: x -> xpT[b][n][c]
__global__ __launch_bounds__(192) void pool_t_kernel(const float* __restrict__ x,
                                                     ushort* __restrict__ xpT) {
    __shared__ float ps[64][49];
    const int gid = blockIdx.x;
    const int ct = gid & 7;          // c-tile (64 channels)
    const int tmp = gid >> 3;
    const int oh = tmp % 48;
    const int b  = tmp / 48;
    const int t = threadIdx.x;
    const int ow = t % 48, ci = t / 48;   // ci 0..3

    const int c0 = ct * 64;
#pragma unroll
    for (int pass = 0; pass < 16; ++pass) {
        const int c = pass * 4 + ci;
        const float* px = x + (((size_t)b * C_ + c0 + c) * H_ + 2 * oh) * W_ + 2 * ow;
        float2 a = *reinterpret_cast<const float2*>(px);
        float2 d = *reinterpret_cast<const float2*>(px + W_);
        ps[c][ow] = fmaxf(fmaxf(a.x, a.y), fmaxf(d.x, d.y));
    }
    __syncthreads();
    const int cc2 = (t & 31) * 2;
    const int nr0 = t >> 5;          // 0..5
#pragma unroll
    for (int pass = 0; pass < 8; ++pass) {
        const int nr = pass * 6 + nr0;     // 0..47
        ushort2 p2;
        p2.x = f2bf(ps[cc2][nr]);
        p2.y = f2bf(ps[cc2 + 1][nr]);
        *reinterpret_cast<ushort2*>(&xpT[((size_t)b * N_ + oh * 48 + nr) * C_ + c0 + cc2]) = p2;
    }
}

// ---------------- prep: pack W2 bf16 | fuse Wfb = bf16(Wr@Ww) | bfuse = Wr@bw
__global__ __launch_bounds__(256) void prep_kernel(const float* __restrict__ Wk,
                                                   const float* __restrict__ Wv,
                                                   const float* __restrict__ Wr,
                                                   const float* __restrict__ Ww,
                                                   const float* __restrict__ bw,
                                                   ushort* __restrict__ W2,
                                                   ushort* __restrict__ Wfb,
                                                   float* __restrict__ bfb) {
    const int blk = blockIdx.x;
    if (blk < 512) {
        const int m = blk;
        const float* src = (m < 256) ? (Wk + (size_t)m * 512) : (Wv + (size_t)(m - 256) * 512);
        const int k = threadIdx.x * 2;
        float2 v = *reinterpret_cast<const float2*>(src + k);
        ushort2 p; p.x = f2bf(v.x); p.y = f2bf(v.y);
        *reinterpret_cast<ushort2*>(&W2[(size_t)m * 512 + k]) = p;
    } else if (blk < 1024) {
        const int o = blk - 512;
        const int v = threadIdx.x;
        float s = 0.f;
        for (int c = 0; c < OD; ++c)
            s = fmaf(Wr[(size_t)o * OD + c], Ww[(size_t)c * VD + v], s);
        Wfb[(size_t)o * VD + v] = f2bf(s);
    } else {
        const int o = (blk - 1024) * 256 + threadIdx.x;
        float s = 0.f;
        for (int c = 0; c < OD; ++c) s = fmaf(Wr[(size_t)o * OD + c], bw[c], s);
        bfb[o] = s;
    }
}

// ------------------------------------- qkv MFMA GEMM (LDS-staged, 2-phase):
// [Wk|Wv](512x512) @ xpT^T -> qkT bf16 [b][n][kd] (BN+ReLU, x SCH) / val bf16 [b][v][n]
__global__ __launch_bounds__(256) void qkv_mfma(
    const ushort* __restrict__ W2, const ushort* __restrict__ xpT,
    const float* __restrict__ kg, const float* __restrict__ kb,
    const float* __restrict__ km, const float* __restrict__ kv,
    const float* __restrict__ bv,
    ushort* __restrict__ qkT, ushort* __restrict__ val) {
    __shared__ ushort Al[2][4096];   // 8KB tile: [kc 2][64 m][32 k], 64B-row swizzled
    __shared__ ushort Bl[2][4096];

    const int id = blockIdx.x;
    const int b = id & 7;
    const int t = id >> 3;           // 0..287
    const int my = t & 7;            // m-tile
    const int nx = t >> 3;           // 0..35
    const int w = threadIdx.x >> 6, l = threadIdx.x & 63;
    const int lr = l & 15, lg = l >> 4;
    const int rbq = (lg * 8) ^ (((lr >> 1) & 3) << 3);

    const ushort* srcA = W2 + (size_t)(my * 64) * 512;              // ld 512
    const ushort* srcB = xpT + ((size_t)b * N_ + nx * 64) * 512;    // ld 512

    auto stage64 = [&](const ushort* src, int koff, char* lbase) {
#pragma unroll
        for (int j = 0; j < 2; ++j) {
            const int prow = j * 64 + w * 16 + (l >> 2);   // 0..127
            const int row = prow & 63;
            const int kc = prow >> 6;
            const int cb = ((l & 3) * 16) ^ (((row >> 1) & 3) << 4);
            const char* s = (const char*)(src + (size_t)row * 512 + koff) + kc * 64 + cb;
            gload_lds16(s, lbase + j * 4096 + w * 1024);
        }
    };

    stage64(srcA, 0, (char*)&Al[0][0]);
    stage64(srcB, 0, (char*)&Bl[0][0]);
    stage64(srcA, 64, (char*)&Al[1][0]);
    stage64(srcB, 64, (char*)&Bl[1][0]);

    f32x4 acc[4];
#pragma unroll
    for (int nt = 0; nt < 4; ++nt) acc[nt] = (f32x4){0.f, 0.f, 0.f, 0.f};

    for (int ks = 0; ks < 8; ++ks) {
        if (ks < 7) { asm volatile("s_waitcnt vmcnt(4)" ::: "memory"); }
        else        { asm volatile("s_waitcnt vmcnt(0)" ::: "memory"); }
        __builtin_amdgcn_s_barrier();
        __builtin_amdgcn_sched_barrier(0);
        const ushort* Ab = &Al[ks & 1][0];
        const ushort* Bb = &Bl[ks & 1][0];
        __builtin_amdgcn_s_setprio(1);
#pragma unroll
        for (int kc = 0; kc < 2; ++kc) {
            bf16x8 af = *reinterpret_cast<const bf16x8*>(Ab + kc * 2048 + (w * 16 + lr) * 32 + rbq);
#pragma unroll
            for (int nt = 0; nt < 4; ++nt) {
                bf16x8 bfr = *reinterpret_cast<const bf16x8*>(Bb + kc * 2048 + (nt * 16 + lr) * 32 + rbq);
                acc[nt] = __builtin_amdgcn_mfma_f32_16x16x32_bf16(af, bfr, acc[nt], 0, 0, 0);
            }
        }
        __builtin_amdgcn_s_setprio(0);
        __builtin_amdgcn_sched_barrier(0);
        __builtin_amdgcn_s_barrier();
        if (ks < 6) {
            stage64(srcA, (ks + 2) * 64, (char*)&Al[ks & 1][0]);
            stage64(srcB, (ks + 2) * 64, (char*)&Bl[ks & 1][0]);
        }
    }

    const int m0 = my * 64 + w * 16;
    if (m0 < 256) {
        float inv[4], add[4];
#pragma unroll
        for (int j = 0; j < 4; ++j) {
            int o = m0 + lg * 4 + j;
            inv[j] = kg[o] * rsqrtf(kv[o] + EPSV);
            add[j] = kb[o] - km[o] * inv[j];
        }
#pragma unroll
        for (int nt = 0; nt < 4; ++nt) {
            int n = nx * 64 + nt * 16 + lr;
            ushort4 q4;
            q4.x = f2bf(fmaxf(acc[nt][0] * inv[0] + add[0], 0.f) * SCH);
            q4.y = f2bf(fmaxf(acc[nt][1] * inv[1] + add[1], 0.f) * SCH);
            q4.z = f2bf(fmaxf(acc[nt][2] * inv[2] + add[2], 0.f) * SCH);
            q4.w = f2bf(fmaxf(acc[nt][3] * inv[3] + add[3], 0.f) * SCH);
            *reinterpret_cast<ushort4*>(&qkT[((size_t)b * N_ + n) * KD + m0 + lg * 4]) = q4;
        }
    } else {
#pragma unroll
        for (int j = 0; j < 4; ++j) {
            int vch = m0 - 256 + lg * 4 + j;
            float bb = bv[vch];
#pragma unroll
            for (int nt = 0; nt < 4; ++nt) {
                int n = nx * 64 + nt * 16 + lr;
                val[((size_t)b * VD + vch) * N_ + n] = f2bf(acc[nt][j] + bb);
            }
        }
    }
}

// ------------------------------------------------------ LDS-staged MFMA flash attention
// Register-blocked: 4 waves / 256 thr; 32 q-rows PER WAVE (2x 16-row subtiles)
// -> each K/V LDS fragment read feeds 2 MFMAs (halves LDS reads per MFMA, the
// measured bottleneck). 128 q-rows/block; 4-way KV split; grid 576; K+V dbuf
// (72KB LDS -> 2 blocks/CU). launch_bounds(256,2): 256-VGPR cap, no spill.
__global__ __launch_bounds__(256, 2) void attn_mfma(const ushort* __restrict__ qkT,
                                                    const ushort* __restrict__ val,
                                                    ushort* __restrict__ part,
                                                    float* __restrict__ pm,
                                                    float* __restrict__ pl) {
    __shared__ ushort Kl[2][8192];   // 2 x 16KB: [kc 8][m 32][32 kd]
    __shared__ ushort Vl[2][8192];   // 2 x 16KB: [v 256][m 32]
    __shared__ ushort Pl[4][1024];   // per-wave P [32 q][32 m]

    const int id = blockIdx.x;
    const int b  = id & 7;           // XCD-pinned batch
    const int rest = id >> 3;        // 0..71
    const int s  = rest & 3;         // KV quarter
    const int qt = rest >> 2;        // 0..17
    const int q0 = qt * 128;
    const int t0 = s * 18;           // first key-tile of this split
    const int w  = threadIdx.x >> 6;
    const int l  = threadIdx.x & 63;
    const int lr = l & 15, lg = l >> 4;

    const ushort* Qb = qkT + (size_t)b * N_ * KD;
    const ushort* Vb = val + (size_t)b * VD * N_;

    const int rb = lr * 32 + ((lg * 8) ^ (((lr >> 1) & 3) << 3));

    // resident Q fragments: 2 subtiles x 16 rows
    bf16x8 qf[2][8];
#pragma unroll
    for (int u = 0; u < 2; ++u) {
        const ushort* qrow = Qb + (size_t)(q0 + w * 32 + u * 16 + lr) * KD + lg * 8;
#pragma unroll
        for (int kc = 0; kc < 8; ++kc)
            qf[u][kc] = *reinterpret_cast<const bf16x8*>(qrow + kc * 32);
    }
    asm volatile("s_waitcnt vmcnt(0)" ::: "memory");

    auto stage_K = [&](int itx, int buf) {
#pragma unroll
        for (int j = 0; j < 4; ++j) {
            const int prow = j * 64 + w * 16 + (l >> 2);   // kc*32 + m
            const int m = prow & 31;
            const int kc = prow >> 5;
            const int cb = ((l & 3) * 16) ^ (((m >> 1) & 3) << 4);
            const char* src = (const char*)Qb + (size_t)(itx * 32 + m) * (KD * 2) + kc * 64 + cb;
            gload_lds16(src, (char*)(&Kl[buf][0]) + j * 4096 + w * 1024);
        }
    };
    auto stage_V = [&](int itx, int buf) {
#pragma unroll
        for (int j = 0; j < 4; ++j) {
            const int r = j * 64 + w * 16 + (l >> 2);      // v-row 0..255
            const int cb = ((l & 3) * 16) ^ (((r >> 1) & 3) << 4);
            const char* src = (const char*)Vb + (size_t)r * (N_ * 2) + itx * 64 + cb;
            gload_lds16(src, (char*)(&Vl[buf][0]) + j * 4096 + w * 1024);
        }
    };

    stage_K(t0, 0);      // per-wave queue (oldest first): K0(4), V0(4), K1(4) = 12
    stage_V(t0, 0);
    stage_K(t0 + 1, 1);

    f32x4 O[2][16];
#pragma unroll
    for (int u = 0; u < 2; ++u)
#pragma unroll
        for (int vt = 0; vt < 16; ++vt) O[u][vt] = (f32x4){0.f, 0.f, 0.f, 0.f};
    f32x4 Ol[2];
    Ol[0] = (f32x4){0.f, 0.f, 0.f, 0.f};
    Ol[1] = (f32x4){0.f, 0.f, 0.f, 0.f};
    float mrun[2][4];
#pragma unroll
    for (int u = 0; u < 2; ++u)
#pragma unroll
        for (int r = 0; r < 4; ++r) mrun[u][r] = -1e30f;
    bf16x8 ones;
#pragma unroll
    for (int i = 0; i < 8; ++i) ones[i] = (short)0x3F80;   // bf16 1.0

    ushort* Pw = &Pl[w][0];

    for (int it = 0; it < 18; ++it) {
        const int cur = it & 1;
        // ---- K(it) ready: steady outstanding {K(it),V(it),K(it+1)}=12 -> 8
        if (it < 17) { asm volatile("s_waitcnt vmcnt(8)" ::: "memory"); }
        else         { asm volatile("s_waitcnt vmcnt(4)" ::: "memory"); }
        __builtin_amdgcn_s_barrier();
        __builtin_amdgcn_sched_barrier(0);
        if (it < 17) stage_V(t0 + it + 1, cur ^ 1);   // buf last read in PV(it-1)

        const ushort* Kc = &Kl[cur][0];

        // ---- S[2][16q x 32m] = Q K^T ; each K-frag read feeds 2 MFMAs
        f32x4 S0[2], S1[2];
#pragma unroll
        for (int u = 0; u < 2; ++u) {
            S0[u] = (f32x4){0.f, 0.f, 0.f, 0.f};
            S1[u] = (f32x4){0.f, 0.f, 0.f, 0.f};
        }
        __builtin_amdgcn_s_setprio(1);
#pragma unroll
        for (int kc = 0; kc < 8; ++kc) {
            bf16x8 k0 = *reinterpret_cast<const bf16x8*>(Kc + kc * 1024 + rb);
            bf16x8 k1 = *reinterpret_cast<const bf16x8*>(Kc + kc * 1024 + 512 + rb);
            S0[0] = __builtin_amdgcn_mfma_f32_16x16x32_bf16(qf[0][kc], k0, S0[0], 0, 0, 0);
            S0[1] = __builtin_amdgcn_mfma_f32_16x16x32_bf16(qf[1][kc], k0, S0[1], 0, 0, 0);
            S1[0] = __builtin_amdgcn_mfma_f32_16x16x32_bf16(qf[0][kc], k1, S1[0], 0, 0, 0);
            S1[1] = __builtin_amdgcn_mfma_f32_16x16x32_bf16(qf[1][kc], k1, S1[1], 0, 0, 0);
        }
        __builtin_amdgcn_s_setprio(0);

        // ---- defer-max: lane-local check only (no cross-lane reduce hot path)
        bool ok = true;
        float lmax[2][4];
#pragma unroll
        for (int u = 0; u < 2; ++u)
#pragma unroll
            for (int r = 0; r < 4; ++r) {
                lmax[u][r] = fmaxf(S0[u][r], S1[u][r]);
                ok = ok && (lmax[u][r] <= mrun[u][r] + 11.5f);   // 11.5 bits ~ e^8
            }
        if (!__all(ok)) {
#pragma unroll
            for (int u = 0; u < 2; ++u) {
                float corr[4];
#pragma unroll
                for (int r = 0; r < 4; ++r) {
                    float m2 = lmax[u][r];
#pragma unroll
                    for (int off = 1; off < 16; off <<= 1) m2 = fmaxf(m2, __shfl_xor(m2, off, 16));
                    const float mn = fmaxf(mrun[u][r], m2);
                    corr[r] = exp2f(mrun[u][r] - mn);
                    mrun[u][r] = mn;
                }
#pragma unroll
                for (int vt = 0; vt < 16; ++vt) {
                    f32x4 o = O[u][vt];
                    o[0] *= corr[0]; o[1] *= corr[1]; o[2] *= corr[2]; o[3] *= corr[3];
                    O[u][vt] = o;
                }
                Ol[u][0] *= corr[0]; Ol[u][1] *= corr[1];
                Ol[u][2] *= corr[2]; Ol[u][3] *= corr[3];
            }
        }
#pragma unroll
        for (int u = 0; u < 2; ++u)
#pragma unroll
            for (int r = 0; r < 4; ++r) {
                const int row = u * 16 + lg * 4 + r;
                const int sw = ((row >> 1) & 3) << 3;
                Pw[row * 32 + (lr ^ sw)] = f2bf(exp2f(S0[u][r] - mrun[u][r]));
                Pw[row * 32 + ((16 + lr) ^ sw)] = f2bf(exp2f(S1[u][r] - mrun[u][r]));
            }

        // ---- V(it) ready: outstanding {V(it),K(it+1),V(it+1)}=12 -> 8
        if (it < 17) { asm volatile("s_waitcnt vmcnt(8)" ::: "memory"); }
        else         { asm volatile("s_waitcnt vmcnt(0)" ::: "memory"); }
        __builtin_amdgcn_s_barrier();
        __builtin_amdgcn_sched_barrier(0);
        if (it < 16) stage_K(t0 + it + 2, cur);       // Kl[cur] free after QK(it)

        // ---- O += P V^T ; l += P ones^T ; each V-frag read feeds 2 MFMAs
        bf16x8 pf0 = *reinterpret_cast<const bf16x8*>(Pw + rb);
        bf16x8 pf1 = *reinterpret_cast<const bf16x8*>(Pw + 512 + rb);
        const ushort* Vc = &Vl[cur][0];
        __builtin_amdgcn_s_setprio(1);
        Ol[0] = __builtin_amdgcn_mfma_f32_16x16x32_bf16(pf0, ones, Ol[0], 0, 0, 0);
        Ol[1] = __builtin_amdgcn_mfma_f32_16x16x32_bf16(pf1, ones, Ol[1], 0, 0, 0);
#pragma unroll
        for (int vt = 0; vt < 16; ++vt) {
            bf16x8 vf = *reinterpret_cast<const bf16x8*>(Vc + vt * 512 + rb);
            O[0][vt] = __builtin_amdgcn_mfma_f32_16x16x32_bf16(pf0, vf, O[0][vt], 0, 0, 0);
            O[1][vt] = __builtin_amdgcn_mfma_f32_16x16x32_bf16(pf1, vf, O[1][vt], 0, 0, 0);
        }
        __builtin_amdgcn_s_setprio(0);
    }

    // ---- epilogue: self-normalized partials (bf16) + per-row (m, l)
#pragma unroll
    for (int u = 0; u < 2; ++u) {
        float il[4];
#pragma unroll
        for (int r = 0; r < 4; ++r) il[r] = 1.0f / Ol[u][r];
        ushort* Pp = part + (((size_t)s * B_ + b) * N_ + q0 + w * 32 + u * 16) * VD;
#pragma unroll
        for (int vt = 0; vt < 16; ++vt) {
#pragma unroll
            for (int j = 0; j < 4; ++j)
                Pp[(size_t)(lg * 4 + j) * VD + vt * 16 + lr] = f2bf(O[u][vt][j] * il[j]);
        }
        if (lr == 0) {
#pragma unroll
            for (int r = 0; r < 4; ++r) {
                const size_t idx = ((size_t)s * B_ + b) * N_ + q0 + w * 32 + u * 16 + lg * 4 + r;
                pm[idx] = mrun[u][r];
                pl[idx] = Ol[u][r];
            }
        }
    }
}

// ---------------------- merge 4 KV-split partials -> ctxT bf16 [b][n][v]
__global__ __launch_bounds__(256) void merge_kernel(const ushort* __restrict__ part,
                                                    const float* __restrict__ pm,
                                                    const float* __restrict__ pl,
                                                    ushort* __restrict__ ctxT) {
    const int row = blockIdx.x * 8 + (threadIdx.x >> 5);   // b*N + n
    const int lane = threadIdx.x & 31;
    const size_t RN = (size_t)B_ * N_;

    float m[NSPLIT], lv[NSPLIT];
#pragma unroll
    for (int si = 0; si < NSPLIT; ++si) {
        m[si]  = pm[si * RN + row];
        lv[si] = pl[si * RN + row];
    }
    float M = fmaxf(fmaxf(m[0], m[1]), fmaxf(m[2], m[3]));
    float wgt[NSPLIT], wsum = 0.f;
#pragma unroll
    for (int si = 0; si < NSPLIT; ++si) {
        wgt[si] = exp2f(m[si] - M) * lv[si];   // log2-domain maxes
        wsum += wgt[si];
    }
    const float inv = 1.0f / wsum;

    float acc[8] = {};
#pragma unroll
    for (int si = 0; si < NSPLIT; ++si) {
        bf16x8 p = *reinterpret_cast<const bf16x8*>(&part[(si * RN + row) * VD + lane * 8]);
        const float ws = wgt[si];
#pragma unroll
        for (int j = 0; j < 8; ++j) acc[j] = fmaf(ws, bf2f((ushort)p[j]), acc[j]);
    }
    ushort4 o0, o1;
    o0.x = f2bf(acc[0] * inv); o0.y = f2bf(acc[1] * inv);
    o0.z = f2bf(acc[2] * inv); o0.w = f2bf(acc[3] * inv);
    o1.x = f2bf(acc[4] * inv); o1.y = f2bf(acc[5] * inv);
    o1.z = f2bf(acc[6] * inv); o1.w = f2bf(acc[7] * inv);
    ushort* dst = ctxT + (size_t)row * VD + lane * 8;
    *reinterpret_cast<ushort4*>(dst) = o0;
    *reinterpret_cast<ushort4*>(dst + 4) = o1;
}

// ------------- out conv MFMA (LDS-staged) + folded BN: Z = bf16(bn(Wfb@ctxT^T + bfuse))
__global__ __launch_bounds__(256) void out_mfma(const ushort* __restrict__ Wfb,
                                                const float* __restrict__ bfuse,
                                                const float* __restrict__ rg,
                                                const float* __restrict__ rbta,
                                                const float* __restrict__ rm,
                                                const float* __restrict__ rv,
                                                const ushort* __restrict__ ctxT,
                                                ushort* __restrict__ Z) {
    __shared__ ushort Al[2][4096];
    __shared__ ushort Bl[2][4096];

    const int id = blockIdx.x;
    const int b = id & 7;
    const int t = id >> 3;           // 0..287
    const int my = t & 7;            // OD tile
    const int nx = t >> 3;           // 0..35
    const int w = threadIdx.x >> 6, l = threadIdx.x & 63;
    const int lr = l & 15, lg = l >> 4;
    const int rbq = (lg * 8) ^ (((lr >> 1) & 3) << 3);

    const ushort* srcA = Wfb + (size_t)(my * 64) * VD;               // ld 256
    const ushort* srcB = ctxT + ((size_t)b * N_ + nx * 64) * VD;     // ld 256

    auto stage64 = [&](const ushort* src, int koff, char* lbase) {
#pragma unroll
        for (int j = 0; j < 2; ++j) {
            const int prow = j * 64 + w * 16 + (l >> 2);
            const int row = prow & 63;
            const int kc = prow >> 6;
            const int cb = ((l & 3) * 16) ^ (((row >> 1) & 3) << 4);
            const char* s = (const char*)(src + (size_t)row * VD + koff) + kc * 64 + cb;
            gload_lds16(s, lbase + j * 4096 + w * 1024);
        }
    };

    stage64(srcA, 0, (char*)&Al[0][0]);
    stage64(srcB, 0, (char*)&Bl[0][0]);
    stage64(srcA, 64, (char*)&Al[1][0]);
    stage64(srcB, 64, (char*)&Bl[1][0]);

    f32x4 acc[4];
#pragma unroll
    for (int nt = 0; nt < 4; ++nt) acc[nt] = (f32x4){0.f, 0.f, 0.f, 0.f};

    for (int ks = 0; ks < 4; ++ks) {
        if (ks < 3) { asm volatile("s_waitcnt vmcnt(4)" ::: "memory"); }
        else        { asm volatile("s_waitcnt vmcnt(0)" ::: "memory"); }
        __builtin_amdgcn_s_barrier();
        __builtin_amdgcn_sched_barrier(0);
        const ushort* Ab = &Al[ks & 1][0];
        const ushort* Bb = &Bl[ks & 1][0];
        __builtin_amdgcn_s_setprio(1);
#pragma unroll
        for (int kc = 0; kc < 2; ++kc) {
            bf16x8 af = *reinterpret_cast<const bf16x8*>(Ab + kc * 2048 + (w * 16 + lr) * 32 + rbq);
#pragma unroll
            for (int nt = 0; nt < 4; ++nt) {
                bf16x8 bfr = *reinterpret_cast<const bf16x8*>(Bb + kc * 2048 + (nt * 16 + lr) * 32 + rbq);
                acc[nt] = __builtin_amdgcn_mfma_f32_16x16x32_bf16(af, bfr, acc[nt], 0, 0, 0);
            }
        }
        __builtin_amdgcn_s_setprio(0);
        __builtin_amdgcn_sched_barrier(0);
        __builtin_amdgcn_s_barrier();
        if (ks < 2) {
            stage64(srcA, (ks + 2) * 64, (char*)&Al[ks & 1][0]);
            stage64(srcB, (ks + 2) * 64, (char*)&Bl[ks & 1][0]);
        }
    }

    const int m0 = my * 64 + w * 16;
#pragma unroll
    for (int j = 0; j < 4; ++j) {
        const int o = m0 + lg * 4 + j;
        const float inv = rg[o] * rsqrtf(rv[o] + EPSV);
        const float add = rbta[o] - rm[o] * inv;
        const float bb = bfuse[o];
#pragma unroll
        for (int nt = 0; nt < 4; ++nt) {
            const int n = nx * 64 + nt * 16 + lr;
            Z[((size_t)b * OD + o) * N_ + n] = f2bf((acc[nt][j] + bb) * inv + add);
        }
    }
}

// --------------------------- bilinear upsample (align_corners) + ReLU, x4 vectorized
__global__ void upsample_kernel(const ushort* __restrict__ Z,
                                float* __restrict__ out) {
    const int total = B_ * OD * H_ * (W_ / 4);
    const float s = 47.0f / 95.0f;
    for (int idx = blockIdx.x * blockDim.x + threadIdx.x; idx < total;
         idx += gridDim.x * blockDim.x) {
        const int xq = idx % 24;
        const int t = idx / 24;
        const int y = t % H_;
        const int bo = t / H_;
        const float fy = y * s;
        const int y0 = (int)fy;
        const int y1 = min(y0 + 1, HP - 1);
        const float wy = fy - y0;
        const ushort* Zp = Z + (size_t)bo * N_;
        const ushort* r0 = Zp + y0 * WP;
        const ushort* r1 = Zp + y1 * WP;
        float4 o4;
        float* po = &o4.x;
#pragma unroll
        for (int j = 0; j < 4; ++j) {
            const int x = xq * 4 + j;
            const float fx = x * s;
            const int x0 = (int)fx;
            const int x1 = min(x0 + 1, WP - 1);
            const float wx = fx - x0;
            float v00 = bf2f(r0[x0]), v01 = bf2f(r0[x1]);
            float v10 = bf2f(r1[x0]), v11 = bf2f(r1[x1]);
            float a = v00 + (v01 - v00) * wx;
            float c = v10 + (v11 - v10) * wx;
            po[j] = fmaxf(a + (c - a) * wy, 0.f);
        }
        *reinterpret_cast<float4*>(out + (size_t)idx * 4) = o4;
    }
}

extern "C" void kernel_launch(void* const* d_in, const int* in_sizes, int n_in,
                              void* d_out, int out_size, void* d_ws, size_t ws_size,
                              hipStream_t stream) {
    const float* x  = (const float*)d_in[0];
    const float* Wk = (const float*)d_in[1];
    const float* kg = (const float*)d_in[2];
    const float* kb = (const float*)d_in[3];
    const float* km = (const float*)d_in[4];
    const float* kvv= (const float*)d_in[5];
    const float* Wv = (const float*)d_in[6];
    const float* bv = (const float*)d_in[7];
    const float* Ww = (const float*)d_in[8];
    const float* bw = (const float*)d_in[9];
    const float* Wr = (const float*)d_in[10];
    const float* rg = (const float*)d_in[11];
    const float* rb = (const float*)d_in[12];
    const float* rm = (const float*)d_in[13];
    const float* rv = (const float*)d_in[14];

    char* wsb = (char*)d_ws;
    ushort* xpT  = (ushort*)(wsb + BOFF_XPT);
    ushort* qkT  = (ushort*)(wsb + BOFF_QKT);
    ushort* valp = (ushort*)(wsb + BOFF_VAL);
    ushort* ctxT = (ushort*)(wsb + BOFF_CTX);
    ushort* W2   = (ushort*)(wsb + BOFF_W2);
    ushort* Wfb  = (ushort*)(wsb + BOFF_WF);
    float*  bfb  = (float*)(wsb + BOFF_BF);
    ushort* part = (ushort*)(wsb + BOFF_PRT);
    float*  pm   = (float*)(wsb + BOFF_PM);
    float*  pl   = (float*)(wsb + BOFF_PL);
    ushort* Z    = (ushort*)(wsb + BOFF_XPT);  // overlays xpT (dead after qkv)
    float*  out  = (float*)d_out;

    pool_t_kernel<<<8 * 48 * 8, 192, 0, stream>>>(x, xpT);
    prep_kernel<<<1026, 256, 0, stream>>>(Wk, Wv, Wr, Ww, bw, W2, Wfb, bfb);
    qkv_mfma<<<2304, 256, 0, stream>>>(W2, xpT, kg, kb, km, kvv, bv, qkT, valp);
    attn_mfma<<<576, 256, 0, stream>>>(qkT, valp, part, pm, pl);
    merge_kernel<<<(B_ * N_) / 8, 256, 0, stream>>>(part, pm, pl, ctxT);
    out_mfma<<<2304, 256, 0, stream>>>(Wfb, bfb, rg, rb, rm, rv, ctxT, Z);
    upsample_kernel<<<4096, 256, 0, stream>>>(Z, out);
}

// Round 10
// 262.667 us; speedup vs baseline: 1.3329x; 1.2762x over previous
//
#include <hip/hip_runtime.h>
#include <math.h>

typedef __attribute__((ext_vector_type(8))) short bf16x8;
typedef __attribute__((ext_vector_type(4))) float f32x4;

namespace {

constexpr int B_ = 8, C_ = 512, H_ = 96, W_ = 96;
constexpr int HP = 48, WP = 48, N_ = HP * WP;   // pooled spatial, N=2304
constexpr int KD = 256, VD = 256, OD = 512;
constexpr int NSPLIT = 4;                        // KV splits
constexpr float EPSV = 1e-5f;
// softmax scale folded into qkT: s = (q*SCH)·(k*SCH) is in exp2 domain
// SCH = sqrt(key_dim^-0.5 * log2(e))
constexpr float SCH = 0.30028060f;

// workspace byte offsets
constexpr size_t BOFF_XPT = 0;                                       // bf16 [B][N][C]
constexpr size_t BOFF_QKT = BOFF_XPT + (size_t)B_ * N_ * C_ * 2;     // bf16 [B][N][KD]
constexpr size_t BOFF_VAL = BOFF_QKT + (size_t)B_ * N_ * KD * 2;     // bf16 [B][VD][N]
constexpr size_t BOFF_CTX = BOFF_VAL + (size_t)B_ * VD * N_ * 2;     // bf16 [B][N][VD]
constexpr size_t BOFF_W2  = BOFF_CTX + (size_t)B_ * N_ * VD * 2;     // bf16 [512][512]
constexpr size_t BOFF_WF  = BOFF_W2  + (size_t)512 * 512 * 2;        // bf16 [OD][VD]
constexpr size_t BOFF_BF  = BOFF_WF  + (size_t)OD * VD * 2;          // fp32 [OD]
constexpr size_t BOFF_PRT = BOFF_BF  + (size_t)OD * 4;               // bf16 [S][B][N][VD]
constexpr size_t BOFF_PM  = BOFF_PRT + (size_t)NSPLIT * B_ * N_ * VD * 2;  // f32 [S][B][N]
constexpr size_t BOFF_PL  = BOFF_PM  + (size_t)NSPLIT * B_ * N_ * 4;       // f32 [S][B][N]
// Z bf16 [B][OD][N] (18.9MB) overlays xpT (18.9MB), dead by then

} // namespace

__device__ __forceinline__ ushort f2bf(float f) {
    union { float f; unsigned u; } x; x.f = f;
    unsigned r = x.u + 0x7FFFu + ((x.u >> 16) & 1u);
    return (ushort)(r >> 16);
}

__device__ __forceinline__ float bf2f(ushort u) {
    union { unsigned u; float f; } x; x.u = ((unsigned)u) << 16;
    return x.f;
}

__device__ __forceinline__ void gload_lds16(const void* g, void* l) {
    __builtin_amdgcn_global_load_lds(
        (const __attribute__((address_space(1))) unsigned int*)g,
        (__attribute__((address_space(3))) unsigned int*)l, 16, 0, 0);
}

// ------------------------ fused maxpool 2x2 + transpose + bf16: x -> xpT[b][n][c]
__global__ __launch_bounds__(192) void pool_t_kernel(const float* __restrict__ x,
                                                     ushort* __restrict__ xpT) {
    __shared__ float ps[64][49];
    const int gid = blockIdx.x;
    const int ct = gid & 7;          // c-tile (64 channels)
    const int tmp = gid >> 3;
    const int oh = tmp % 48;
    const int b  = tmp / 48;
    const int t = threadIdx.x;
    const int ow = t % 48, ci = t / 48;   // ci 0..3

    const int c0 = ct * 64;
#pragma unroll
    for (int pass = 0; pass < 16; ++pass) {
        const int c = pass * 4 + ci;
        const float* px = x + (((size_t)b * C_ + c0 + c) * H_ + 2 * oh) * W_ + 2 * ow;
        float2 a = *reinterpret_cast<const float2*>(px);
        float2 d = *reinterpret_cast<const float2*>(px + W_);
        ps[c][ow] = fmaxf(fmaxf(a.x, a.y), fmaxf(d.x, d.y));
    }
    __syncthreads();
    const int cc2 = (t & 31) * 2;
    const int nr0 = t >> 5;          // 0..5
#pragma unroll
    for (int pass = 0; pass < 8; ++pass) {
        const int nr = pass * 6 + nr0;     // 0..47
        ushort2 p2;
        p2.x = f2bf(ps[cc2][nr]);
        p2.y = f2bf(ps[cc2 + 1][nr]);
        *reinterpret_cast<ushort2*>(&xpT[((size_t)b * N_ + oh * 48 + nr) * C_ + c0 + cc2]) = p2;
    }
}

// ---------------- prep: pack W2 bf16 | fuse Wfb = bf16(Wr@Ww) | bfuse = Wr@bw
__global__ __launch_bounds__(256) void prep_kernel(const float* __restrict__ Wk,
                                                   const float* __restrict__ Wv,
                                                   const float* __restrict__ Wr,
                                                   const float* __restrict__ Ww,
                                                   const float* __restrict__ bw,
                                                   ushort* __restrict__ W2,
                                                   ushort* __restrict__ Wfb,
                                                   float* __restrict__ bfb) {
    const int blk = blockIdx.x;
    if (blk < 512) {
        const int m = blk;
        const float* src = (m < 256) ? (Wk + (size_t)m * 512) : (Wv + (size_t)(m - 256) * 512);
        const int k = threadIdx.x * 2;
        float2 v = *reinterpret_cast<const float2*>(src + k);
        ushort2 p; p.x = f2bf(v.x); p.y = f2bf(v.y);
        *reinterpret_cast<ushort2*>(&W2[(size_t)m * 512 + k]) = p;
    } else if (blk < 1024) {
        const int o = blk - 512;
        const int v = threadIdx.x;
        float s = 0.f;
        for (int c = 0; c < OD; ++c)
            s = fmaf(Wr[(size_t)o * OD + c], Ww[(size_t)c * VD + v], s);
        Wfb[(size_t)o * VD + v] = f2bf(s);
    } else {
        const int o = (blk - 1024) * 256 + threadIdx.x;
        float s = 0.f;
        for (int c = 0; c < OD; ++c) s = fmaf(Wr[(size_t)o * OD + c], bw[c], s);
        bfb[o] = s;
    }
}

// ------------------------------------- qkv MFMA GEMM (LDS-staged, 2-phase):
// [Wk|Wv](512x512) @ xpT^T -> qkT bf16 [b][n][kd] (BN+ReLU, x SCH) / val bf16 [b][v][n]
__global__ __launch_bounds__(256) void qkv_mfma(
    const ushort* __restrict__ W2, const ushort* __restrict__ xpT,
    const float* __restrict__ kg, const float* __restrict__ kb,
    const float* __restrict__ km, const float* __restrict__ kv,
    const float* __restrict__ bv,
    ushort* __restrict__ qkT, ushort* __restrict__ val) {
    __shared__ ushort Al[2][4096];   // 8KB tile: [kc 2][64 m][32 k], 64B-row swizzled
    __shared__ ushort Bl[2][4096];

    const int id = blockIdx.x;
    const int b = id & 7;
    const int t = id >> 3;           // 0..287
    const int my = t & 7;            // m-tile
    const int nx = t >> 3;           // 0..35
    const int w = threadIdx.x >> 6, l = threadIdx.x & 63;
    const int lr = l & 15, lg = l >> 4;
    const int rbq = (lg * 8) ^ (((lr >> 1) & 3) << 3);

    const ushort* srcA = W2 + (size_t)(my * 64) * 512;              // ld 512
    const ushort* srcB = xpT + ((size_t)b * N_ + nx * 64) * 512;    // ld 512

    auto stage64 = [&](const ushort* src, int koff, char* lbase) {
#pragma unroll
        for (int j = 0; j < 2; ++j) {
            const int prow = j * 64 + w * 16 + (l >> 2);   // 0..127
            const int row = prow & 63;
            const int kc = prow >> 6;
            const int cb = ((l & 3) * 16) ^ (((row >> 1) & 3) << 4);
            const char* s = (const char*)(src + (size_t)row * 512 + koff) + kc * 64 + cb;
            gload_lds16(s, lbase + j * 4096 + w * 1024);
        }
    };

    stage64(srcA, 0, (char*)&Al[0][0]);
    stage64(srcB, 0, (char*)&Bl[0][0]);
    stage64(srcA, 64, (char*)&Al[1][0]);
    stage64(srcB, 64, (char*)&Bl[1][0]);

    f32x4 acc[4];
#pragma unroll
    for (int nt = 0; nt < 4; ++nt) acc[nt] = (f32x4){0.f, 0.f, 0.f, 0.f};

    for (int ks = 0; ks < 8; ++ks) {
        if (ks < 7) { asm volatile("s_waitcnt vmcnt(4)" ::: "memory"); }
        else        { asm volatile("s_waitcnt vmcnt(0)" ::: "memory"); }
        __builtin_amdgcn_s_barrier();
        __builtin_amdgcn_sched_barrier(0);
        const ushort* Ab = &Al[ks & 1][0];
        const ushort* Bb = &Bl[ks & 1][0];
        __builtin_amdgcn_s_setprio(1);
#pragma unroll
        for (int kc = 0; kc < 2; ++kc) {
            bf16x8 af = *reinterpret_cast<const bf16x8*>(Ab + kc * 2048 + (w * 16 + lr) * 32 + rbq);
#pragma unroll
            for (int nt = 0; nt < 4; ++nt) {
                bf16x8 bfr = *reinterpret_cast<const bf16x8*>(Bb + kc * 2048 + (nt * 16 + lr) * 32 + rbq);
                acc[nt] = __builtin_amdgcn_mfma_f32_16x16x32_bf16(af, bfr, acc[nt], 0, 0, 0);
            }
        }
        __builtin_amdgcn_s_setprio(0);
        __builtin_amdgcn_sched_barrier(0);
        __builtin_amdgcn_s_barrier();
        if (ks < 6) {
            stage64(srcA, (ks + 2) * 64, (char*)&Al[ks & 1][0]);
            stage64(srcB, (ks + 2) * 64, (char*)&Bl[ks & 1][0]);
        }
    }

    const int m0 = my * 64 + w * 16;
    if (m0 < 256) {
        float inv[4], add[4];
#pragma unroll
        for (int j = 0; j < 4; ++j) {
            int o = m0 + lg * 4 + j;
            inv[j] = kg[o] * rsqrtf(kv[o] + EPSV);
            add[j] = kb[o] - km[o] * inv[j];
        }
#pragma unroll
        for (int nt = 0; nt < 4; ++nt) {
            int n = nx * 64 + nt * 16 + lr;
            ushort4 q4;
            q4.x = f2bf(fmaxf(acc[nt][0] * inv[0] + add[0], 0.f) * SCH);
            q4.y = f2bf(fmaxf(acc[nt][1] * inv[1] + add[1], 0.f) * SCH);
            q4.z = f2bf(fmaxf(acc[nt][2] * inv[2] + add[2], 0.f) * SCH);
            q4.w = f2bf(fmaxf(acc[nt][3] * inv[3] + add[3], 0.f) * SCH);
            *reinterpret_cast<ushort4*>(&qkT[((size_t)b * N_ + n) * KD + m0 + lg * 4]) = q4;
        }
    } else {
#pragma unroll
        for (int j = 0; j < 4; ++j) {
            int vch = m0 - 256 + lg * 4 + j;
            float bb = bv[vch];
#pragma unroll
            for (int nt = 0; nt < 4; ++nt) {
                int n = nx * 64 + nt * 16 + lr;
                val[((size_t)b * VD + vch) * N_ + n] = f2bf(acc[nt][j] + bb);
            }
        }
    }
}

// ------------------------------------------------------ LDS-staged MFMA flash attention
// R6-proven structure: 4 waves / 256 thr; 64 q-rows/block; 4-way KV split
// (grid 1152, 18 tiles of 32 keys). K double-buffered, V single-buffered
// (staged post-PV-barrier) -> 53KB LDS, 3 blocks/CU. exp2-domain softmax
// (scale folded into qkT), lane-local defer-max, ones-MFMA row-sum.
__global__ __launch_bounds__(256, 3) void attn_mfma(const ushort* __restrict__ qkT,
                                                    const ushort* __restrict__ val,
                                                    ushort* __restrict__ part,
                                                    float* __restrict__ pm,
                                                    float* __restrict__ pl) {
    __shared__ ushort Kl[2][8192];   // 2 x 16KB: [kc 8][m 32][32 kd]
    __shared__ ushort Vl[8192];      // 16KB: [v 256][m 32]
    __shared__ ushort Pl[4][512];    // per-wave P [16 q][32 m]

    const int id = blockIdx.x;
    const int b  = id & 7;           // XCD-pinned batch
    const int rest = id >> 3;        // 0..143
    const int s  = rest & 3;         // KV quarter
    const int qt = rest >> 2;        // 0..35
    const int q0 = qt * 64;
    const int t0 = s * 18;           // first key-tile of this split
    const int w  = threadIdx.x >> 6;
    const int l  = threadIdx.x & 63;
    const int lr = l & 15, lg = l >> 4;

    const ushort* Qb = qkT + (size_t)b * N_ * KD;
    const ushort* Vb = val + (size_t)b * VD * N_;

    // shared per-lane swizzled read base (u16 units) for K/V/P 64B-row subtiles
    const int rb = lr * 32 + ((lg * 8) ^ (((lr >> 1) & 3) << 3));

    // resident Q fragments
    bf16x8 qf[8];
    {
        const ushort* qrow = Qb + (size_t)(q0 + w * 16 + lr) * KD + lg * 8;
#pragma unroll
        for (int kc = 0; kc < 8; ++kc)
            qf[kc] = *reinterpret_cast<const bf16x8*>(qrow + kc * 32);
    }
    asm volatile("s_waitcnt vmcnt(0)" ::: "memory");

    auto stage_K = [&](int itx, int buf) {
#pragma unroll
        for (int j = 0; j < 4; ++j) {
            const int prow = j * 64 + w * 16 + (l >> 2);   // kc*32 + m
            const int m = prow & 31;
            const int kc = prow >> 5;
            const int cb = ((l & 3) * 16) ^ (((m >> 1) & 3) << 4);
            const char* src = (const char*)Qb + (size_t)(itx * 32 + m) * (KD * 2) + kc * 64 + cb;
            gload_lds16(src, (char*)(&Kl[buf][0]) + j * 4096 + w * 1024);
        }
    };
    auto stage_V = [&](int itx) {
#pragma unroll
        for (int j = 0; j < 4; ++j) {
            const int r = j * 64 + w * 16 + (l >> 2);      // v-row 0..255
            const int cb = ((l & 3) * 16) ^ (((r >> 1) & 3) << 4);
            const char* src = (const char*)Vb + (size_t)r * (N_ * 2) + itx * 64 + cb;
            gload_lds16(src, (char*)(&Vl[0]) + j * 4096 + w * 1024);
        }
    };

    stage_K(t0, 0);      // queue (oldest first): K0, V0, K1 -> 12 outstanding
    stage_V(t0);
    stage_K(t0 + 1, 1);

    f32x4 O[16];
#pragma unroll
    for (int vt = 0; vt < 16; ++vt) O[vt] = (f32x4){0.f, 0.f, 0.f, 0.f};
    f32x4 Ol = (f32x4){0.f, 0.f, 0.f, 0.f};     // P row-sum accumulator (l)
    float mrun[4] = {-1e30f, -1e30f, -1e30f, -1e30f};   // log2 domain
    bf16x8 ones;
#pragma unroll
    for (int i = 0; i < 8; ++i) ones[i] = (short)0x3F80;   // bf16 1.0

    ushort* Pw = &Pl[w][0];

    for (int it = 0; it < 18; ++it) {
        const int cur = it & 1;
        // ---- K(it) ready
        if (it < 17) { asm volatile("s_waitcnt vmcnt(8)" ::: "memory"); }
        else         { asm volatile("s_waitcnt vmcnt(4)" ::: "memory"); }
        __builtin_amdgcn_s_barrier();
        __builtin_amdgcn_sched_barrier(0);

        const ushort* Kc = &Kl[cur][0];

        // ---- S[16q x 32m] = Q K^T  (exp2 domain: scale folded into qkT)
        f32x4 S0 = (f32x4){0.f, 0.f, 0.f, 0.f};
        f32x4 S1 = (f32x4){0.f, 0.f, 0.f, 0.f};
        __builtin_amdgcn_s_setprio(1);
#pragma unroll
        for (int kc = 0; kc < 8; ++kc) {
            bf16x8 k0 = *reinterpret_cast<const bf16x8*>(Kc + kc * 1024 + rb);
            bf16x8 k1 = *reinterpret_cast<const bf16x8*>(Kc + kc * 1024 + 512 + rb);
            S0 = __builtin_amdgcn_mfma_f32_16x16x32_bf16(qf[kc], k0, S0, 0, 0, 0);
            S1 = __builtin_amdgcn_mfma_f32_16x16x32_bf16(qf[kc], k1, S1, 0, 0, 0);
        }
        __builtin_amdgcn_s_setprio(0);

        // ---- defer-max: lane-local check (no cross-lane reduce on hot path)
        float lmax[4];
        bool ok = true;
#pragma unroll
        for (int r = 0; r < 4; ++r) {
            lmax[r] = fmaxf(S0[r], S1[r]);
            ok = ok && (lmax[r] <= mrun[r] + 11.5f);   // 11.5 bits ~ e^8
        }
        if (!__all(ok)) {
            float corr[4];
#pragma unroll
            for (int r = 0; r < 4; ++r) {
                float m2 = lmax[r];
#pragma unroll
                for (int off = 1; off < 16; off <<= 1) m2 = fmaxf(m2, __shfl_xor(m2, off, 16));
                const float mn = fmaxf(mrun[r], m2);
                corr[r] = exp2f(mrun[r] - mn);
                mrun[r] = mn;
            }
#pragma unroll
            for (int vt = 0; vt < 16; ++vt) {
                f32x4 o = O[vt];
                o[0] *= corr[0]; o[1] *= corr[1]; o[2] *= corr[2]; o[3] *= corr[3];
                O[vt] = o;
            }
            Ol[0] *= corr[0]; Ol[1] *= corr[1]; Ol[2] *= corr[2]; Ol[3] *= corr[3];
        }
#pragma unroll
        for (int r = 0; r < 4; ++r) {
            const int row = lg * 4 + r;
            const int sw = ((row >> 1) & 3) << 3;
            Pw[row * 32 + (lr ^ sw)] = f2bf(exp2f(S0[r] - mrun[r]));
            Pw[row * 32 + ((16 + lr) ^ sw)] = f2bf(exp2f(S1[r] - mrun[r]));
        }

        // ---- V(it) ready
        if (it < 17) { asm volatile("s_waitcnt vmcnt(4)" ::: "memory"); }
        else         { asm volatile("s_waitcnt vmcnt(0)" ::: "memory"); }
        __builtin_amdgcn_s_barrier();
        __builtin_amdgcn_sched_barrier(0);

        // ---- O += P V^T ; l += P ones^T
        bf16x8 pf = *reinterpret_cast<const bf16x8*>(Pw + rb);
        __builtin_amdgcn_s_setprio(1);
        Ol = __builtin_amdgcn_mfma_f32_16x16x32_bf16(pf, ones, Ol, 0, 0, 0);
#pragma unroll
        for (int vt = 0; vt < 16; ++vt) {
            bf16x8 vf = *reinterpret_cast<const bf16x8*>(Vl + vt * 512 + rb);
            O[vt] = __builtin_amdgcn_mfma_f32_16x16x32_bf16(pf, vf, O[vt], 0, 0, 0);
        }
        __builtin_amdgcn_s_setprio(0);

        __builtin_amdgcn_sched_barrier(0);
        __builtin_amdgcn_s_barrier();               // all waves done reading Vl & Kl[cur]
        if (it < 17) stage_V(t0 + it + 1);
        if (it < 16) stage_K(t0 + it + 2, cur);
    }

    // ---- epilogue: self-normalized partial (bf16) + per-row (m, l)
    float il[4];
#pragma unroll
    for (int r = 0; r < 4; ++r) il[r] = 1.0f / Ol[r];
    ushort* Pp = part + (((size_t)s * B_ + b) * N_ + q0 + w * 16) * VD;
#pragma unroll
    for (int vt = 0; vt < 16; ++vt) {
#pragma unroll
        for (int j = 0; j < 4; ++j)
            Pp[(size_t)(lg * 4 + j) * VD + vt * 16 + lr] = f2bf(O[vt][j] * il[j]);
    }
    if (lr == 0) {
#pragma unroll
        for (int r = 0; r < 4; ++r) {
            const size_t idx = ((size_t)s * B_ + b) * N_ + q0 + w * 16 + lg * 4 + r;
            pm[idx] = mrun[r];
            pl[idx] = Ol[r];
        }
    }
}

// ---------------------- merge 4 KV-split partials -> ctxT bf16 [b][n][v]
__global__ __launch_bounds__(256) void merge_kernel(const ushort* __restrict__ part,
                                                    const float* __restrict__ pm,
                                                    const float* __restrict__ pl,
                                                    ushort* __restrict__ ctxT) {
    const int row = blockIdx.x * 8 + (threadIdx.x >> 5);   // b*N + n
    const int lane = threadIdx.x & 31;
    const size_t RN = (size_t)B_ * N_;

    float m[NSPLIT], lv[NSPLIT];
#pragma unroll
    for (int si = 0; si < NSPLIT; ++si) {
        m[si]  = pm[si * RN + row];
        lv[si] = pl[si * RN + row];
    }
    float M = fmaxf(fmaxf(m[0], m[1]), fmaxf(m[2], m[3]));
    float wgt[NSPLIT], wsum = 0.f;
#pragma unroll
    for (int si = 0; si < NSPLIT; ++si) {
        wgt[si] = exp2f(m[si] - M) * lv[si];   // log2-domain maxes
        wsum += wgt[si];
    }
    const float inv = 1.0f / wsum;

    float acc[8] = {};
#pragma unroll
    for (int si = 0; si < NSPLIT; ++si) {
        bf16x8 p = *reinterpret_cast<const bf16x8*>(&part[(si * RN + row) * VD + lane * 8]);
        const float ws = wgt[si];
#pragma unroll
        for (int j = 0; j < 8; ++j) acc[j] = fmaf(ws, bf2f((ushort)p[j]), acc[j]);
    }
    ushort4 o0, o1;
    o0.x = f2bf(acc[0] * inv); o0.y = f2bf(acc[1] * inv);
    o0.z = f2bf(acc[2] * inv); o0.w = f2bf(acc[3] * inv);
    o1.x = f2bf(acc[4] * inv); o1.y = f2bf(acc[5] * inv);
    o1.z = f2bf(acc[6] * inv); o1.w = f2bf(acc[7] * inv);
    ushort* dst = ctxT + (size_t)row * VD + lane * 8;
    *reinterpret_cast<ushort4*>(dst) = o0;
    *reinterpret_cast<ushort4*>(dst + 4) = o1;
}

// ------------- out conv MFMA (LDS-staged) + folded BN: Z = bf16(bn(Wfb@ctxT^T + bfuse))
__global__ __launch_bounds__(256) void out_mfma(const ushort* __restrict__ Wfb,
                                                const float* __restrict__ bfuse,
                                                const float* __restrict__ rg,
                                                const float* __restrict__ rbta,
                                                const float* __restrict__ rm,
                                                const float* __restrict__ rv,
                                                const ushort* __restrict__ ctxT,
                                                ushort* __restrict__ Z) {
    __shared__ ushort Al[2][4096];
    __shared__ ushort Bl[2][4096];

    const int id = blockIdx.x;
    const int b = id & 7;
    const int t = id >> 3;           // 0..287
    const int my = t & 7;            // OD tile
    const int nx = t >> 3;           // 0..35
    const int w = threadIdx.x >> 6, l = threadIdx.x & 63;
    const int lr = l & 15, lg = l >> 4;
    const int rbq = (lg * 8) ^ (((lr >> 1) & 3) << 3);

    const ushort* srcA = Wfb + (size_t)(my * 64) * VD;               // ld 256
    const ushort* srcB = ctxT + ((size_t)b * N_ + nx * 64) * VD;     // ld 256

    auto stage64 = [&](const ushort* src, int koff, char* lbase) {
#pragma unroll
        for (int j = 0; j < 2; ++j) {
            const int prow = j * 64 + w * 16 + (l >> 2);
            const int row = prow & 63;
            const int kc = prow >> 6;
            const int cb = ((l & 3) * 16) ^ (((row >> 1) & 3) << 4);
            const char* s = (const char*)(src + (size_t)row * VD + koff) + kc * 64 + cb;
            gload_lds16(s, lbase + j * 4096 + w * 1024);
        }
    };

    stage64(srcA, 0, (char*)&Al[0][0]);
    stage64(srcB, 0, (char*)&Bl[0][0]);
    stage64(srcA, 64, (char*)&Al[1][0]);
    stage64(srcB, 64, (char*)&Bl[1][0]);

    f32x4 acc[4];
#pragma unroll
    for (int nt = 0; nt < 4; ++nt) acc[nt] = (f32x4){0.f, 0.f, 0.f, 0.f};

    for (int ks = 0; ks < 4; ++ks) {
        if (ks < 3) { asm volatile("s_waitcnt vmcnt(4)" ::: "memory"); }
        else        { asm volatile("s_waitcnt vmcnt(0)" ::: "memory"); }
        __builtin_amdgcn_s_barrier();
        __builtin_amdgcn_sched_barrier(0);
        const ushort* Ab = &Al[ks & 1][0];
        const ushort* Bb = &Bl[ks & 1][0];
        __builtin_amdgcn_s_setprio(1);
#pragma unroll
        for (int kc = 0; kc < 2; ++kc) {
            bf16x8 af = *reinterpret_cast<const bf16x8*>(Ab + kc * 2048 + (w * 16 + lr) * 32 + rbq);
#pragma unroll
            for (int nt = 0; nt < 4; ++nt) {
                bf16x8 bfr = *reinterpret_cast<const bf16x8*>(Bb + kc * 2048 + (nt * 16 + lr) * 32 + rbq);
                acc[nt] = __builtin_amdgcn_mfma_f32_16x16x32_bf16(af, bfr, acc[nt], 0, 0, 0);
            }
        }
        __builtin_amdgcn_s_setprio(0);
        __builtin_amdgcn_sched_barrier(0);
        __builtin_amdgcn_s_barrier();
        if (ks < 2) {
            stage64(srcA, (ks + 2) * 64, (char*)&Al[ks & 1][0]);
            stage64(srcB, (ks + 2) * 64, (char*)&Bl[ks & 1][0]);
        }
    }

    const int m0 = my * 64 + w * 16;
#pragma unroll
    for (int j = 0; j < 4; ++j) {
        const int o = m0 + lg * 4 + j;
        const float inv = rg[o] * rsqrtf(rv[o] + EPSV);
        const float add = rbta[o] - rm[o] * inv;
        const float bb = bfuse[o];
#pragma unroll
        for (int nt = 0; nt < 4; ++nt) {
            const int n = nx * 64 + nt * 16 + lr;
            Z[((size_t)b * OD + o) * N_ + n] = f2bf((acc[nt][j] + bb) * inv + add);
        }
    }
}

// --------------------------- bilinear upsample (align_corners) + ReLU, x4 vectorized
__global__ void upsample_kernel(const ushort* __restrict__ Z,
                                float* __restrict__ out) {
    const int total = B_ * OD * H_ * (W_ / 4);
    const float s = 47.0f / 95.0f;
    for (int idx = blockIdx.x * blockDim.x + threadIdx.x; idx < total;
         idx += gridDim.x * blockDim.x) {
        const int xq = idx % 24;
        const int t = idx / 24;
        const int y = t % H_;
        const int bo = t / H_;
        const float fy = y * s;
        const int y0 = (int)fy;
        const int y1 = min(y0 + 1, HP - 1);
        const float wy = fy - y0;
        const ushort* Zp = Z + (size_t)bo * N_;
        const ushort* r0 = Zp + y0 * WP;
        const ushort* r1 = Zp + y1 * WP;
        float4 o4;
        float* po = &o4.x;
#pragma unroll
        for (int j = 0; j < 4; ++j) {
            const int x = xq * 4 + j;
            const float fx = x * s;
            const int x0 = (int)fx;
            const int x1 = min(x0 + 1, WP - 1);
            const float wx = fx - x0;
            float v00 = bf2f(r0[x0]), v01 = bf2f(r0[x1]);
            float v10 = bf2f(r1[x0]), v11 = bf2f(r1[x1]);
            float a = v00 + (v01 - v00) * wx;
            float c = v10 + (v11 - v10) * wx;
            po[j] = fmaxf(a + (c - a) * wy, 0.f);
        }
        *reinterpret_cast<float4*>(out + (size_t)idx * 4) = o4;
    }
}

extern "C" void kernel_launch(void* const* d_in, const int* in_sizes, int n_in,
                              void* d_out, int out_size, void* d_ws, size_t ws_size,
                              hipStream_t stream) {
    const float* x  = (const float*)d_in[0];
    const float* Wk = (const float*)d_in[1];
    const float* kg = (const float*)d_in[2];
    const float* kb = (const float*)d_in[3];
    const float* km = (const float*)d_in[4];
    const float* kvv= (const float*)d_in[5];
    const float* Wv = (const float*)d_in[6];
    const float* bv = (const float*)d_in[7];
    const float* Ww = (const float*)d_in[8];
    const float* bw = (const float*)d_in[9];
    const float* Wr = (const float*)d_in[10];
    const float* rg = (const float*)d_in[11];
    const float* rb = (const float*)d_in[12];
    const float* rm = (const float*)d_in[13];
    const float* rv = (const float*)d_in[14];

    char* wsb = (char*)d_ws;
    ushort* xpT  = (ushort*)(wsb + BOFF_XPT);
    ushort* qkT  = (ushort*)(wsb + BOFF_QKT);
    ushort* valp = (ushort*)(wsb + BOFF_VAL);
    ushort* ctxT = (ushort*)(wsb + BOFF_CTX);
    ushort* W2   = (ushort*)(wsb + BOFF_W2);
    ushort* Wfb  = (ushort*)(wsb + BOFF_WF);
    float*  bfb  = (float*)(wsb + BOFF_BF);
    ushort* part = (ushort*)(wsb + BOFF_PRT);
    float*  pm   = (float*)(wsb + BOFF_PM);
    float*  pl   = (float*)(wsb + BOFF_PL);
    ushort* Z    = (ushort*)(wsb + BOFF_XPT);  // overlays xpT (dead after qkv)
    float*  out  = (float*)d_out;

    pool_t_kernel<<<8 * 48 * 8, 192, 0, stream>>>(x, xpT);
    prep_kernel<<<1026, 256, 0, stream>>>(Wk, Wv, Wr, Ww, bw, W2, Wfb, bfb);
    qkv_mfma<<<2304, 256, 0, stream>>>(W2, xpT, kg, kb, km, kvv, bv, qkT, valp);
    attn_mfma<<<1152, 256, 0, stream>>>(qkT, valp, part, pm, pl);
    merge_kernel<<<(B_ * N_) / 8, 256, 0, stream>>>(part, pm, pl, ctxT);
    out_mfma<<<2304, 256, 0, stream>>>(Wfb, bfb, rg, rb, rm, rv, ctxT, Z);
    upsample_kernel<<<4096, 256, 0, stream>>>(Z, out);
}